// Round 1
// 441.813 us; speedup vs baseline: 1.0128x; 1.0128x over previous
//
#include <hip/hip_runtime.h>

typedef unsigned short u16;
typedef __attribute__((ext_vector_type(8))) short short8;
typedef __attribute__((ext_vector_type(4))) float floatx4;

__device__ __forceinline__ float bf2f(u16 v){
  union { unsigned int u; float f; } x; x.u = ((unsigned int)v) << 16; return x.f;
}
__device__ __forceinline__ u16 f2bf(float f){
  union { float f; unsigned int u; } x; x.f = f;
  unsigned int r = x.u + 0x7FFFu + ((x.u >> 16) & 1u);
  return (u16)(r >> 16);
}
__device__ __forceinline__ short8 cvt8(float4 f0, float4 f1){
  short8 v;
  v[0] = (short)f2bf(f0.x); v[1] = (short)f2bf(f0.y);
  v[2] = (short)f2bf(f0.z); v[3] = (short)f2bf(f0.w);
  v[4] = (short)f2bf(f1.x); v[5] = (short)f2bf(f1.y);
  v[6] = (short)f2bf(f1.z); v[7] = (short)f2bf(f1.w);
  return v;
}

__device__ __forceinline__ void async16(const void* g, void* l){
  __builtin_amdgcn_global_load_lds(
      (__attribute__((address_space(1))) unsigned int*)const_cast<void*>(g),
      (__attribute__((address_space(3))) unsigned int*)l, 16, 0, 0);
}

// -------- weight transpose: fp32 in [R][C] -> bf16 out [C][R] ---------------
__global__ void transpose_f32(const float* __restrict__ in, u16* __restrict__ out,
                              int R, int C){
  __shared__ u16 t[32][33];
  const int tx = threadIdx.x;
  const int c0 = blockIdx.x * 32, r0 = blockIdx.y * 32;
  for (int i = tx; i < 1024; i += 256){
    int r = i >> 5, c = i & 31;
    t[r][c] = f2bf(in[(size_t)(r0 + r) * C + c0 + c]);
  }
  __syncthreads();
  for (int i = tx; i < 1024; i += 256){
    int r = i >> 5, c = i & 31;
    out[(size_t)(c0 + r) * R + r0 + c] = t[c][r];
  }
}

// -------- expand relative-position bias: fp32 table -> bf16 Bm[h][q][k] -----
__global__ void bias_expand(const float* __restrict__ table, u16* __restrict__ Bm){
  int i = blockIdx.x * 256 + threadIdx.x;   // 65536 (q,k) pairs
  int q = i >> 8, k = i & 255;
  int rh = (q >> 4) - (k >> 4) + 15;
  int rw = (q & 15) - (k & 15) + 15;
  int idx = rh * 31 + rw;                   // [0, 960]
  #pragma unroll
  for (int h = 0; h < 8; h++) Bm[h * 65536 + i] = f2bf(table[(size_t)idx * 8 + h]);
}

// ---------------- GEMM: C[M,N] = A[M,512] x Bt[N,512]^T ---------------------
// 128x128 tile, BK=64, XOR-chunk-swizzled LDS (slot c ^= r&7).
// R1: double-buffered LDS 2-phase pipeline (stage t+1 before compute t; one
//     barrier/K-step whose implicit vmcnt(0) drain lands AFTER the MFMAs) +
//     bijective XCD swizzle (col-tiles sharing an A-panel land on one XCD).
// A_FP32: A is fp32 -> reg-staged float4 prefetch + cvt + ds_write post-MFMA.
// MODE 0: write Q permuted [b][h][n][d] (bf16)
// MODE 1: write K [b][h][n][d] and V^T [b][h][d][n] (bf16)
// MODE 2: write fp32 out[row][col] = v + proj_b[col]
template<int MODE, bool A_FP32>
__global__ __launch_bounds__(256)
void gemm_bt(const void* __restrict__ A, const u16* __restrict__ Bt,
             void* __restrict__ O0, u16* __restrict__ O1,
             const float* __restrict__ bias)
{
  __shared__ __align__(16) u16 As[2][128 * 64];
  __shared__ __align__(16) u16 Bs[2][128 * 64];
  const int tid  = threadIdx.x;
  const int lane = tid & 63, wave = tid >> 6;
  const int q16  = lane & 15, quad = lane >> 4;
  const int wr   = wave >> 1, wc = wave & 1;

  // XCD-aware swizzle: launch-linear bid -> logical tile id such that each
  // XCD (bid%8) owns a CONTIGUOUS run of logical ids; logical order is
  // col-fastest, so the col-tiles sharing one A-panel share one XCD L2.
  constexpr int GX  = (MODE == 1) ? 8 : 4;       // gridDim.x (col tiles)
  constexpr int LGX = (MODE == 1) ? 3 : 2;
  constexpr int CPX = GX * 32;                   // (GX*256)/8 ids per XCD
  const int bid = blockIdx.y * GX + blockIdx.x;  // launch order (x fastest)
  const int swz = (bid & 7) * CPX + (bid >> 3);  // bijective: nwg % 8 == 0
  const int rowBase = (swz >> LGX) * 128;
  const int colBase = (swz & (GX - 1)) * 128;

  const u16*   Ab16 = (const u16*)A   + (size_t)rowBase * 512;
  const float* Af32 = (const float*)A + (size_t)rowBase * 512;
  const u16*   Bw   = Bt + (size_t)colBase * 512;

  floatx4 acc[4][4];
  #pragma unroll
  for (int i = 0; i < 4; i++)
    #pragma unroll
    for (int j = 0; j < 4; j++) acc[i][j] = floatx4{0.f, 0.f, 0.f, 0.f};

  int sr[4], sc[4];
  #pragma unroll
  for (int j = 0; j < 4; j++){
    int p = tid + j * 256;                 // LDS slot this lane fills
    sr[j] = p >> 3;                        // tile row
    sc[j] = ((p & 7) ^ (sr[j] & 7)) * 8;   // swizzled global chunk (elements)
  }

  // ---- prologue: stage K-tile 0 into buffer 0 ----
  if (A_FP32){
    #pragma unroll
    for (int j = 0; j < 4; j++){
      const float* src = Af32 + (size_t)sr[j] * 512 + sc[j];
      float4 f0 = ((const float4*)src)[0];
      float4 f1 = ((const float4*)src)[1];
      *(short8*)(&As[0][(size_t)(tid + j * 256) * 8]) = cvt8(f0, f1);
    }
  } else {
    #pragma unroll
    for (int j = 0; j < 4; j++){
      u16* dA = &As[0][(size_t)(j * 256 + wave * 64) * 8];  // wave-uniform base
      async16(Ab16 + (size_t)sr[j] * 512 + sc[j], dA);
    }
  }
  #pragma unroll
  for (int j = 0; j < 4; j++){
    u16* dB = &Bs[0][(size_t)(j * 256 + wave * 64) * 8];
    async16(Bw + (size_t)sr[j] * 512 + sc[j], dB);
  }
  __syncthreads();

  int cur = 0;
  for (int kt = 0; kt < 8; kt++){   // K=512, BK=64
    const int nb = cur ^ 1;

    // ---- phase 1: issue next tile's loads (no wait) ----
    float4 f0[4], f1[4];
    if (kt < 7){
      if (A_FP32){
        #pragma unroll
        for (int j = 0; j < 4; j++){
          const float* src = Af32 + (size_t)sr[j] * 512 + (kt + 1) * 64 + sc[j];
          f0[j] = ((const float4*)src)[0];
          f1[j] = ((const float4*)src)[1];
        }
      } else {
        #pragma unroll
        for (int j = 0; j < 4; j++){
          u16* dA = &As[nb][(size_t)(j * 256 + wave * 64) * 8];
          async16(Ab16 + (size_t)sr[j] * 512 + (kt + 1) * 64 + sc[j], dA);
        }
      }
      #pragma unroll
      for (int j = 0; j < 4; j++){
        u16* dB = &Bs[nb][(size_t)(j * 256 + wave * 64) * 8];
        async16(Bw + (size_t)sr[j] * 512 + (kt + 1) * 64 + sc[j], dB);
      }
    }

    // ---- phase 2: compute current tile (hides the loads just issued) ----
    #pragma unroll
    for (int kk = 0; kk < 2; kk++){
      short8 af[4], bfr[4];
      #pragma unroll
      for (int mt = 0; mt < 4; mt++){
        int r  = wr * 64 + mt * 16 + q16;
        int ph = ((kk * 4 + quad) ^ (r & 7)) * 8;
        af[mt] = *(const short8*)(&As[cur][r * 64 + ph]);
      }
      #pragma unroll
      for (int nt = 0; nt < 4; nt++){
        int r  = wc * 64 + nt * 16 + q16;
        int ph = ((kk * 4 + quad) ^ (r & 7)) * 8;
        bfr[nt] = *(const short8*)(&Bs[cur][r * 64 + ph]);
      }
      #pragma unroll
      for (int mt = 0; mt < 4; mt++)
        #pragma unroll
        for (int nt = 0; nt < 4; nt++)
          acc[mt][nt] = __builtin_amdgcn_mfma_f32_16x16x32_bf16(
              af[mt], bfr[nt], acc[mt][nt], 0, 0, 0);
    }

    // ---- phase 3 (fp32 A only): loads have landed under MFMA; cvt + write ----
    if (A_FP32 && kt < 7){
      #pragma unroll
      for (int j = 0; j < 4; j++)
        *(short8*)(&As[nb][(size_t)(tid + j * 256) * 8]) = cvt8(f0[j], f1[j]);
    }

    __syncthreads();   // implicit vmcnt(0)+lgkmcnt(0) drain AFTER compute
    cur = nb;
  }

  #pragma unroll
  for (int mt = 0; mt < 4; mt++){
    #pragma unroll
    for (int nt = 0; nt < 4; nt++){
      const floatx4 v = acc[mt][nt];
      const int col = colBase + wc * 64 + nt * 16 + q16;
      #pragma unroll
      for (int r = 0; r < 4; r++){
        const int row = rowBase + wr * 64 + mt * 16 + quad * 4 + r;
        if (MODE == 0){
          int bb = row >> 8, n = row & 255, hh = col >> 6, dd = col & 63;
          ((u16*)O0)[(((size_t)(bb * 8 + hh)) * 256 + n) * 64 + dd] = f2bf(v[r]);
        } else if (MODE == 1){
          int bb = row >> 8, key = row & 255;
          int two = col >> 9, hh = (col >> 6) & 7, dd = col & 63;
          if (two == 0)
            ((u16*)O0)[(((size_t)(bb * 8 + hh)) * 256 + key) * 64 + dd] = f2bf(v[r]);
          else
            O1[(((size_t)(bb * 8 + hh)) * 64 + dd) * 256 + key] = f2bf(v[r]);
        } else {
          ((float*)O0)[(size_t)row * 512 + col] = v[r] + bias[col];
        }
      }
    }
  }
}

// ---------------- fused MFMA attention: one block per (b,h) -----------------
// Validated: R2 (this kernel) produced output identical to naive R3/R4.
__global__ __launch_bounds__(256)
void attn_kernel(const u16* __restrict__ Qb, const u16* __restrict__ Kb,
                 const u16* __restrict__ Vtb, const u16* __restrict__ Bm,
                 u16* __restrict__ Ob)
{
  constexpr int PS = 264;                       // 256 + 8 pad, rows 16B-aligned
  __shared__ __align__(16) u16 Vs[64 * PS];
  __shared__ __align__(16) u16 Pss[4 * 16 * PS];
  const int bh = blockIdx.x;
  const int b = bh >> 3, h = bh & 7;
  const u16* Qp = Qb  + (size_t)bh * 256 * 64;
  const u16* Kp = Kb  + (size_t)bh * 256 * 64;
  const u16* Vp = Vtb + (size_t)bh * 64 * 256;
  const u16* Bp = Bm  + (size_t)h * 65536;
  const int tid = threadIdx.x;
  const int lane = tid & 63, wave = tid >> 6;
  const int q16 = lane & 15, quad = lane >> 4;
  u16* Pw = Pss + wave * 16 * PS;

  for (int i = tid; i < 64 * 32; i += 256){     // stage V^T, padded rows
    int dd = i >> 5, kc = (i & 31) * 8;
    *(short8*)(Vs + dd * PS + kc) = *(const short8*)(Vp + dd * 256 + kc);
  }
  __syncthreads();

  for (int chunk = 0; chunk < 4; chunk++){
    const int qbase = wave * 64 + chunk * 16;
    const short8 qa0 = *(const short8*)(Qp + (qbase + q16) * 64 + quad * 8);
    const short8 qa1 = *(const short8*)(Qp + (qbase + q16) * 64 + 32 + quad * 8);

    floatx4 acc[16];
    #pragma unroll
    for (int kt = 0; kt < 16; kt++) acc[kt] = floatx4{0.f, 0.f, 0.f, 0.f};
    #pragma unroll
    for (int kt = 0; kt < 16; kt++){
      const u16* kr = Kp + (kt * 16 + q16) * 64 + quad * 8;
      acc[kt] = __builtin_amdgcn_mfma_f32_16x16x32_bf16(
          qa0, *(const short8*)(kr), acc[kt], 0, 0, 0);
      acc[kt] = __builtin_amdgcn_mfma_f32_16x16x32_bf16(
          qa1, *(const short8*)(kr + 32), acc[kt], 0, 0, 0);
    }

    floatx4 mrow = {-3e38f, -3e38f, -3e38f, -3e38f};
    #pragma unroll
    for (int kt = 0; kt < 16; kt++){
      const u16* bb = Bp + (qbase + quad * 4) * 256 + kt * 16 + q16;
      floatx4 v = acc[kt];
      #pragma unroll
      for (int r = 0; r < 4; r++){
        float t = v[r] * 0.125f + bf2f(bb[(size_t)r * 256]);
        v[r] = t;
        mrow[r] = fmaxf(mrow[r], t);
      }
      acc[kt] = v;
    }
    #pragma unroll
    for (int off = 1; off < 16; off <<= 1){
      #pragma unroll
      for (int r = 0; r < 4; r++)
        mrow[r] = fmaxf(mrow[r], __shfl_xor(mrow[r], off, 64));
    }

    floatx4 lrow = {0.f, 0.f, 0.f, 0.f};
    #pragma unroll
    for (int kt = 0; kt < 16; kt++){
      floatx4 v = acc[kt];
      #pragma unroll
      for (int r = 0; r < 4; r++){
        float e = exp2f((v[r] - mrow[r]) * 1.4426950408889634f);
        v[r] = e;
        lrow[r] += e;
      }
      #pragma unroll
      for (int r = 0; r < 4; r++)
        Pw[(quad * 4 + r) * PS + kt * 16 + q16] = f2bf(v[r]);
    }
    #pragma unroll
    for (int off = 1; off < 16; off <<= 1){
      #pragma unroll
      for (int r = 0; r < 4; r++) lrow[r] += __shfl_xor(lrow[r], off, 64);
    }

    __syncthreads();

    short8 pa[8];
    #pragma unroll
    for (int k2 = 0; k2 < 8; k2++)
      pa[k2] = *(const short8*)(Pw + q16 * PS + k2 * 32 + quad * 8);
    floatx4 o[4];
    #pragma unroll
    for (int nt = 0; nt < 4; nt++) o[nt] = floatx4{0.f, 0.f, 0.f, 0.f};
    #pragma unroll
    for (int nt = 0; nt < 4; nt++)
      #pragma unroll
      for (int k2 = 0; k2 < 8; k2++){
        const short8 vb = *(const short8*)(Vs + (nt * 16 + q16) * PS + k2 * 32 + quad * 8);
        o[nt] = __builtin_amdgcn_mfma_f32_16x16x32_bf16(pa[k2], vb, o[nt], 0, 0, 0);
      }

    floatx4 rl;
    #pragma unroll
    for (int r = 0; r < 4; r++) rl[r] = 1.0f / lrow[r];
    #pragma unroll
    for (int nt = 0; nt < 4; nt++)
      #pragma unroll
      for (int r = 0; r < 4; r++){
        int q = qbase + quad * 4 + r;
        Ob[((size_t)(b * 256 + q)) * 512 + h * 64 + nt * 16 + q16] =
            f2bf(o[nt][r] * rl[r]);
      }
  }
}

extern "C" void kernel_launch(void* const* d_in, const int* in_sizes, int n_in,
                              void* d_out, int out_size, void* d_ws, size_t ws_size,
                              hipStream_t stream)
{
  (void)in_sizes; (void)n_in; (void)out_size; (void)ws_size;
  const float* x      = (const float*)d_in[0];
  const float* y      = (const float*)d_in[1];
  const float* q_w    = (const float*)d_in[2];
  const float* kv_w   = (const float*)d_in[3];
  const float* proj_w = (const float*)d_in[4];
  const float* proj_b = (const float*)d_in[5];
  const float* btab   = (const float*)d_in[6];
  float* out = (float*)d_out;                   // fp32 output per reference
  char* w = (char*)d_ws;

  // workspace layout (total 137,363,456 B)
  u16* Qb   = (u16*)(w);                    // [B,H,256,64] bf16
  u16* Kb   = (u16*)(w + 33554432);         // [B,H,256,64]
  u16* Vtb  = (u16*)(w + 67108864);         // [B,H,64,256]
  u16* Ab   = (u16*)(w + 100663296);        // [B*N,512] bf16
  u16* qwT  = (u16*)(w + 134217728);        // [512,512]
  u16* kvwT = (u16*)(w + 134742016);        // [1024,512]
  u16* pwT  = (u16*)(w + 135790592);        // [512,512]
  u16* Bm   = (u16*)(w + 136314880);        // [8,256,256]

  transpose_f32<<<dim3(16, 16), 256, 0, stream>>>(q_w,    qwT,  512, 512);
  transpose_f32<<<dim3(32, 16), 256, 0, stream>>>(kv_w,   kvwT, 512, 1024);
  transpose_f32<<<dim3(16, 16), 256, 0, stream>>>(proj_w, pwT,  512, 512);
  bias_expand<<<dim3(256), 256, 0, stream>>>(btab, Bm);

  gemm_bt<0, true ><<<dim3(4, 256), 256, 0, stream>>>(x,  qwT,  Qb,  nullptr, nullptr);
  gemm_bt<1, true ><<<dim3(8, 256), 256, 0, stream>>>(y,  kvwT, Kb,  Vtb,     nullptr);
  attn_kernel<<<dim3(1024), 256, 0, stream>>>(Qb, Kb, Vtb, Bm, Ab);
  gemm_bt<2, false><<<dim3(4, 256), 256, 0, stream>>>(Ab, pwT,  out, nullptr, proj_b);
}

// Round 2
// 410.764 us; speedup vs baseline: 1.0894x; 1.0756x over previous
//
#include <hip/hip_runtime.h>

typedef unsigned short u16;
typedef __attribute__((ext_vector_type(8))) short short8;
typedef __attribute__((ext_vector_type(4))) float floatx4;

__device__ __forceinline__ float bf2f(u16 v){
  union { unsigned int u; float f; } x; x.u = ((unsigned int)v) << 16; return x.f;
}
__device__ __forceinline__ u16 f2bf(float f){
  union { float f; unsigned int u; } x; x.f = f;
  unsigned int r = x.u + 0x7FFFu + ((x.u >> 16) & 1u);
  return (u16)(r >> 16);
}
__device__ __forceinline__ short8 cvt8(float4 f0, float4 f1){
  short8 v;
  v[0] = (short)f2bf(f0.x); v[1] = (short)f2bf(f0.y);
  v[2] = (short)f2bf(f0.z); v[3] = (short)f2bf(f0.w);
  v[4] = (short)f2bf(f1.x); v[5] = (short)f2bf(f1.y);
  v[6] = (short)f2bf(f1.z); v[7] = (short)f2bf(f1.w);
  return v;
}

__device__ __forceinline__ void async16(const void* g, void* l){
  __builtin_amdgcn_global_load_lds(
      (__attribute__((address_space(1))) unsigned int*)const_cast<void*>(g),
      (__attribute__((address_space(3))) unsigned int*)l, 16, 0, 0);
}

// -------- fp32 -> bf16 bulk convert (memory-bound, ~16 us per tensor) -------
__global__ __launch_bounds__(256)
void conv_bf16(const float* __restrict__ in, u16* __restrict__ out, int n8){
  const int stride = gridDim.x * 256;
  for (int i = blockIdx.x * 256 + threadIdx.x; i < n8; i += stride){
    float4 f0 = ((const float4*)in)[(size_t)i * 2];
    float4 f1 = ((const float4*)in)[(size_t)i * 2 + 1];
    *(short8*)(out + (size_t)i * 8) = cvt8(f0, f1);
  }
}

// -------- weight transpose: fp32 in [R][C] -> bf16 out [C][R] ---------------
__global__ void transpose_f32(const float* __restrict__ in, u16* __restrict__ out,
                              int R, int C){
  __shared__ u16 t[32][33];
  const int tx = threadIdx.x;
  const int c0 = blockIdx.x * 32, r0 = blockIdx.y * 32;
  for (int i = tx; i < 1024; i += 256){
    int r = i >> 5, c = i & 31;
    t[r][c] = f2bf(in[(size_t)(r0 + r) * C + c0 + c]);
  }
  __syncthreads();
  for (int i = tx; i < 1024; i += 256){
    int r = i >> 5, c = i & 31;
    out[(size_t)(c0 + r) * R + r0 + c] = t[c][r];
  }
}

// -------- expand relative-position bias: fp32 table -> bf16 Bm[h][q][k] -----
__global__ void bias_expand(const float* __restrict__ table, u16* __restrict__ Bm){
  int i = blockIdx.x * 256 + threadIdx.x;   // 65536 (q,k) pairs
  int q = i >> 8, k = i & 255;
  int rh = (q >> 4) - (k >> 4) + 15;
  int rw = (q & 15) - (k & 15) + 15;
  int idx = rh * 31 + rw;                   // [0, 960]
  #pragma unroll
  for (int h = 0; h < 8; h++) Bm[h * 65536 + i] = f2bf(table[(size_t)idx * 8 + h]);
}

// ---------------- GEMM: C[M,N] = A[M,512] x Bt[N,512]^T ---------------------
// R2: 256x128 tile, BK=64, 8 waves (512 thr, 4Mx2N wave grid), 3 LDS staging
// slots (144 KB), counted-vmcnt pipeline: {reading t | ready t+1 | filling
// t+2}, one raw s_barrier per K-step, s_waitcnt vmcnt(6) (never 0 except the
// last iter). XOR-chunk LDS swizzle (slot c ^= r&7, 0 bank conflicts measured)
// + bijective XCD swizzle (col-tiles sharing an A-panel land on one XCD).
// A and Bt are both bf16 (fp32 inputs pre-converted by conv_bf16).
// MODE 0: write Q permuted [b][h][n][d] (bf16)
// MODE 1: write K [b][h][n][d] and V^T [b][h][d][n] (bf16)
// MODE 2: write fp32 out[row][col] = v + proj_b[col]
template<int MODE, int GX>
__global__ __launch_bounds__(512, 2)
void gemm_bt(const u16* __restrict__ A, const u16* __restrict__ Bt,
             void* __restrict__ O0, u16* __restrict__ O1,
             const float* __restrict__ bias)
{
  __shared__ __align__(16) u16 As[3][256 * 64];   // 96 KB
  __shared__ __align__(16) u16 Bs[3][128 * 64];   // 48 KB
  const int tid  = threadIdx.x;
  const int lane = tid & 63, wave = tid >> 6;
  const int q16  = lane & 15, quad = lane >> 4;
  const int wr   = wave >> 1, wc = wave & 1;      // 4M x 2N wave tiles (64x64)

  constexpr int NWG = 128 * GX;                   // M/256=128 row tiles always
  constexpr int CPX = NWG / 8;                    // ids per XCD (NWG%8==0)
  const int bid = blockIdx.x;
  const int swz = (bid & 7) * CPX + (bid >> 3);   // bijective XCD swizzle
  const int rowBase = (swz / GX) * 256;
  const int colBase = (swz % GX) * 128;

  const u16* Ap = A  + (size_t)rowBase * 512;
  const u16* Bp = Bt + (size_t)colBase * 512;

  floatx4 acc[4][4];
  #pragma unroll
  for (int i = 0; i < 4; i++)
    #pragma unroll
    for (int j = 0; j < 4; j++) acc[i][j] = floatx4{0.f, 0.f, 0.f, 0.f};

  // staging geometry: linear LDS slot p -> tile row p>>3, swizzled src chunk
  int sra[4], sca[4];
  #pragma unroll
  for (int j = 0; j < 4; j++){
    int p = tid + j * 512;
    sra[j] = p >> 3;
    sca[j] = ((p & 7) ^ (sra[j] & 7)) * 8;
  }

  // per-tile staging: A = 4 async16/thread, B = 2 async16/thread (6 vmem ops)
  auto STAGE = [&](int slot, int kt){
    #pragma unroll
    for (int j = 0; j < 4; j++){
      u16* d = &As[slot][(size_t)(j * 512 + wave * 64) * 8];
      async16(Ap + (size_t)sra[j] * 512 + kt * 64 + sca[j], d);
    }
    #pragma unroll
    for (int j = 0; j < 2; j++){
      u16* d = &Bs[slot][(size_t)(j * 512 + wave * 64) * 8];
      async16(Bp + (size_t)sra[j] * 512 + kt * 64 + sca[j], d);
    }
  };

  // prologue: two tiles in flight (12 outstanding vmem ops)
  STAGE(0, 0);
  STAGE(1, 1);

  #pragma unroll
  for (int kt = 0; kt < 8; kt++){                 // K=512, BK=64
    const int cs = kt % 3;
    // tile kt complete when all but the newest 6 (tile kt+1) have retired
    if (kt < 7) asm volatile("s_waitcnt vmcnt(6)" ::: "memory");
    else        asm volatile("s_waitcnt vmcnt(0)" ::: "memory");
    __builtin_amdgcn_s_barrier();                 // publish slot cs; also: all
    __builtin_amdgcn_sched_barrier(0);            // waves done reading slot
                                                  // (kt-1)%3 == (kt+2)%3
    if (kt + 2 < 8) STAGE((kt + 2) % 3, kt + 2);  // fill the freed slot
    __builtin_amdgcn_sched_barrier(0);            // pin issue-early

    __builtin_amdgcn_s_setprio(1);
    #pragma unroll
    for (int kk = 0; kk < 2; kk++){
      short8 af[4], bfr[4];
      #pragma unroll
      for (int mt = 0; mt < 4; mt++){
        int r  = wr * 64 + mt * 16 + q16;
        int ph = ((kk * 4 + quad) ^ (r & 7)) * 8;
        af[mt] = *(const short8*)(&As[cs][r * 64 + ph]);
      }
      #pragma unroll
      for (int nt = 0; nt < 4; nt++){
        int r  = wc * 64 + nt * 16 + q16;
        int ph = ((kk * 4 + quad) ^ (r & 7)) * 8;
        bfr[nt] = *(const short8*)(&Bs[cs][r * 64 + ph]);
      }
      #pragma unroll
      for (int mt = 0; mt < 4; mt++)
        #pragma unroll
        for (int nt = 0; nt < 4; nt++)
          acc[mt][nt] = __builtin_amdgcn_mfma_f32_16x16x32_bf16(
              af[mt], bfr[nt], acc[mt][nt], 0, 0, 0);
    }
    __builtin_amdgcn_s_setprio(0);
  }

  #pragma unroll
  for (int mt = 0; mt < 4; mt++){
    #pragma unroll
    for (int nt = 0; nt < 4; nt++){
      const floatx4 v = acc[mt][nt];
      const int col = colBase + wc * 64 + nt * 16 + q16;
      #pragma unroll
      for (int r = 0; r < 4; r++){
        const int row = rowBase + wr * 64 + mt * 16 + quad * 4 + r;
        if (MODE == 0){
          int bb = row >> 8, n = row & 255, hh = col >> 6, dd = col & 63;
          ((u16*)O0)[(((size_t)(bb * 8 + hh)) * 256 + n) * 64 + dd] = f2bf(v[r]);
        } else if (MODE == 1){
          int bb = row >> 8, key = row & 255;
          int two = col >> 9, hh = (col >> 6) & 7, dd = col & 63;
          if (two == 0)
            ((u16*)O0)[(((size_t)(bb * 8 + hh)) * 256 + key) * 64 + dd] = f2bf(v[r]);
          else
            O1[(((size_t)(bb * 8 + hh)) * 64 + dd) * 256 + key] = f2bf(v[r]);
        } else {
          ((float*)O0)[(size_t)row * 512 + col] = v[r] + bias[col];
        }
      }
    }
  }
}

// ---------------- fused MFMA attention: one block per (b,h) -----------------
// Validated: produced output identical to naive reference kernels.
__global__ __launch_bounds__(256)
void attn_kernel(const u16* __restrict__ Qb, const u16* __restrict__ Kb,
                 const u16* __restrict__ Vtb, const u16* __restrict__ Bm,
                 u16* __restrict__ Ob)
{
  constexpr int PS = 264;                       // 256 + 8 pad, rows 16B-aligned
  __shared__ __align__(16) u16 Vs[64 * PS];
  __shared__ __align__(16) u16 Pss[4 * 16 * PS];
  const int bh = blockIdx.x;
  const int b = bh >> 3, h = bh & 7;
  const u16* Qp = Qb  + (size_t)bh * 256 * 64;
  const u16* Kp = Kb  + (size_t)bh * 256 * 64;
  const u16* Vp = Vtb + (size_t)bh * 64 * 256;
  const u16* Bp = Bm  + (size_t)h * 65536;
  const int tid = threadIdx.x;
  const int lane = tid & 63, wave = tid >> 6;
  const int q16 = lane & 15, quad = lane >> 4;
  u16* Pw = Pss + wave * 16 * PS;

  for (int i = tid; i < 64 * 32; i += 256){     // stage V^T, padded rows
    int dd = i >> 5, kc = (i & 31) * 8;
    *(short8*)(Vs + dd * PS + kc) = *(const short8*)(Vp + dd * 256 + kc);
  }
  __syncthreads();

  for (int chunk = 0; chunk < 4; chunk++){
    const int qbase = wave * 64 + chunk * 16;
    const short8 qa0 = *(const short8*)(Qp + (qbase + q16) * 64 + quad * 8);
    const short8 qa1 = *(const short8*)(Qp + (qbase + q16) * 64 + 32 + quad * 8);

    floatx4 acc[16];
    #pragma unroll
    for (int kt = 0; kt < 16; kt++) acc[kt] = floatx4{0.f, 0.f, 0.f, 0.f};
    #pragma unroll
    for (int kt = 0; kt < 16; kt++){
      const u16* kr = Kp + (kt * 16 + q16) * 64 + quad * 8;
      acc[kt] = __builtin_amdgcn_mfma_f32_16x16x32_bf16(
          qa0, *(const short8*)(kr), acc[kt], 0, 0, 0);
      acc[kt] = __builtin_amdgcn_mfma_f32_16x16x32_bf16(
          qa1, *(const short8*)(kr + 32), acc[kt], 0, 0, 0);
    }

    floatx4 mrow = {-3e38f, -3e38f, -3e38f, -3e38f};
    #pragma unroll
    for (int kt = 0; kt < 16; kt++){
      const u16* bb = Bp + (qbase + quad * 4) * 256 + kt * 16 + q16;
      floatx4 v = acc[kt];
      #pragma unroll
      for (int r = 0; r < 4; r++){
        float t = v[r] * 0.125f + bf2f(bb[(size_t)r * 256]);
        v[r] = t;
        mrow[r] = fmaxf(mrow[r], t);
      }
      acc[kt] = v;
    }
    #pragma unroll
    for (int off = 1; off < 16; off <<= 1){
      #pragma unroll
      for (int r = 0; r < 4; r++)
        mrow[r] = fmaxf(mrow[r], __shfl_xor(mrow[r], off, 64));
    }

    floatx4 lrow = {0.f, 0.f, 0.f, 0.f};
    #pragma unroll
    for (int kt = 0; kt < 16; kt++){
      floatx4 v = acc[kt];
      #pragma unroll
      for (int r = 0; r < 4; r++){
        float e = exp2f((v[r] - mrow[r]) * 1.4426950408889634f);
        v[r] = e;
        lrow[r] += e;
      }
      #pragma unroll
      for (int r = 0; r < 4; r++)
        Pw[(quad * 4 + r) * PS + kt * 16 + q16] = f2bf(v[r]);
    }
    #pragma unroll
    for (int off = 1; off < 16; off <<= 1){
      #pragma unroll
      for (int r = 0; r < 4; r++) lrow[r] += __shfl_xor(lrow[r], off, 64);
    }

    __syncthreads();

    short8 pa[8];
    #pragma unroll
    for (int k2 = 0; k2 < 8; k2++)
      pa[k2] = *(const short8*)(Pw + q16 * PS + k2 * 32 + quad * 8);
    floatx4 o[4];
    #pragma unroll
    for (int nt = 0; nt < 4; nt++) o[nt] = floatx4{0.f, 0.f, 0.f, 0.f};
    #pragma unroll
    for (int nt = 0; nt < 4; nt++)
      #pragma unroll
      for (int k2 = 0; k2 < 8; k2++){
        const short8 vb = *(const short8*)(Vs + (nt * 16 + q16) * PS + k2 * 32 + quad * 8);
        o[nt] = __builtin_amdgcn_mfma_f32_16x16x32_bf16(pa[k2], vb, o[nt], 0, 0, 0);
      }

    floatx4 rl;
    #pragma unroll
    for (int r = 0; r < 4; r++) rl[r] = 1.0f / lrow[r];
    #pragma unroll
    for (int nt = 0; nt < 4; nt++)
      #pragma unroll
      for (int r = 0; r < 4; r++){
        int q = qbase + quad * 4 + r;
        Ob[((size_t)(b * 256 + q)) * 512 + h * 64 + nt * 16 + q16] =
            f2bf(o[nt][r] * rl[r]);
      }
  }
}

extern "C" void kernel_launch(void* const* d_in, const int* in_sizes, int n_in,
                              void* d_out, int out_size, void* d_ws, size_t ws_size,
                              hipStream_t stream)
{
  (void)in_sizes; (void)n_in; (void)out_size; (void)ws_size;
  const float* x      = (const float*)d_in[0];
  const float* y      = (const float*)d_in[1];
  const float* q_w    = (const float*)d_in[2];
  const float* kv_w   = (const float*)d_in[3];
  const float* proj_w = (const float*)d_in[4];
  const float* proj_b = (const float*)d_in[5];
  const float* btab   = (const float*)d_in[6];
  float* out = (float*)d_out;                   // fp32 output per reference
  char* w = (char*)d_ws;

  // workspace layout (total 137,363,456 B)
  u16* Qb   = (u16*)(w);                    // [B,H,256,64] bf16
  u16* Kb   = (u16*)(w + 33554432);         // [B,H,256,64]
  u16* Vtb  = (u16*)(w + 67108864);         // [B,H,64,256]
  u16* Ab   = (u16*)(w + 100663296);        // [B*N,512] bf16 (xb / yb / attn-out)
  u16* qwT  = (u16*)(w + 134217728);        // [512,512]
  u16* kvwT = (u16*)(w + 134742016);        // [1024,512]
  u16* pwT  = (u16*)(w + 135790592);        // [512,512]
  u16* Bm   = (u16*)(w + 136314880);        // [8,256,256]

  transpose_f32<<<dim3(16, 16), 256, 0, stream>>>(q_w,    qwT,  512, 512);
  transpose_f32<<<dim3(32, 16), 256, 0, stream>>>(kv_w,   kvwT, 512, 1024);
  transpose_f32<<<dim3(16, 16), 256, 0, stream>>>(proj_w, pwT,  512, 512);
  bias_expand<<<dim3(256), 256, 0, stream>>>(btab, Bm);

  // xb lives in the Ab slot until Q-gemm consumes it; then yb overwrites it;
  // attn later overwrites the slot again with its bf16 output (yb is dead).
  conv_bf16<<<dim3(2048), 256, 0, stream>>>(x, Ab, 2097152);
  gemm_bt<0, 4><<<dim3(512),  512, 0, stream>>>(Ab, qwT,  Qb,  nullptr, nullptr);
  conv_bf16<<<dim3(2048), 256, 0, stream>>>(y, Ab, 2097152);
  gemm_bt<1, 8><<<dim3(1024), 512, 0, stream>>>(Ab, kvwT, Kb,  Vtb,     nullptr);
  attn_kernel<<<dim3(1024), 256, 0, stream>>>(Qb, Kb, Vtb, Bm, Ab);
  gemm_bt<2, 4><<<dim3(512),  512, 0, stream>>>(Ab, pwT,  out, nullptr, proj_b);
}